// Round 6
// baseline (441.740 us; speedup 1.0000x reference)
//
#include <hip/hip_runtime.h>
#include <math.h>

#define BB 128
#define NN 128
#define DIN 1024
#define H1 256
#define DOUT 32
#define KCL 8
#define NPTS 128
#define MROWS (BB*NN)   // 16384
#define CSTR 130        // centsT row stride (words, init staging only)
#define RSTR 132        // cost/G row stride (words, 16B aligned)
#define HSTR 257        // fused-mlp2 h-chunk row stride (odd -> conflict-free b32 reads)
#define DEADKEY 0xFFFFFFFF00000000ull

__device__ __forceinline__ float gelu_exact(float v) {
    return 0.5f * v * (1.0f + erff(v * 0.70710678118654752f));
}

__device__ __forceinline__ unsigned long long mkkey(float v, int r, int j) {
    return ((unsigned long long)__float_as_uint(v) << 32) | (unsigned)((r << 7) | j);
}

__device__ __forceinline__ float readlanef(float v, int lane) {
    return __int_as_float(__builtin_amdgcn_readlane(__float_as_int(v), lane));
}

// u32 min via DPP (costs are >=0 floats: IEEE order == unsigned bit order)
template<int CTRL, int RMASK>
__device__ __forceinline__ unsigned dpp_umin_step(unsigned v) {
    unsigned t = (unsigned)__builtin_amdgcn_update_dpp((int)v, (int)v, CTRL, RMASK, 0xf, false);
    return t < v ? t : v;
}
__device__ __forceinline__ unsigned wave_umin_bcast(unsigned v) {
    v = dpp_umin_step<0x111, 0xf>(v);
    v = dpp_umin_step<0x112, 0xf>(v);
    v = dpp_umin_step<0x114, 0xf>(v);
    v = dpp_umin_step<0x118, 0xf>(v);
    v = dpp_umin_step<0x142, 0xa>(v);
    v = dpp_umin_step<0x143, 0xc>(v);
    return (unsigned)__builtin_amdgcn_readlane((int)v, 63);
}
// lane31 = min(lanes0..31), lane63 = min(lanes32..63)
__device__ __forceinline__ unsigned half_umin(unsigned v) {
    v = dpp_umin_step<0x111, 0xf>(v);
    v = dpp_umin_step<0x112, 0xf>(v);
    v = dpp_umin_step<0x114, 0xf>(v);
    v = dpp_umin_step<0x118, 0xf>(v);
    v = dpp_umin_step<0x142, 0xa>(v);
    return v;
}

// ---------------- gelu precompute: gx = gelu(x), memory-bound ----------------
__global__ __launch_bounds__(256) void gelu_kernel(const float* __restrict__ x,
                                                   float* __restrict__ gx, int n4) {
    int i = blockIdx.x * 256 + threadIdx.x;
    const int stride = gridDim.x * 256;
    for (; i < n4; i += stride) {
        float4 v = ((const float4*)x)[i];
        v.x = gelu_exact(v.x);
        v.y = gelu_exact(v.y);
        v.z = gelu_exact(v.z);
        v.w = gelu_exact(v.w);
        ((float4*)gx)[i] = v;
    }
}

// ---------------- GEMM1: h = A @ W1 + b1 ; R0 structure (64x64, BK=32, grid 1024) ----------------
// FUSE=true: A = gelu(x) applied at staging (fallback). FUSE=false: A = gx (pre-gelu'd).
// NOTE: 3 microtile/tile-geometry variants (R2/R3/R5) all failed to beat this; the bound is
// the 2-barrier-per-K-step staging structure, not LDS-read bytes. Keep frozen.
template<bool FUSE>
__global__ __launch_bounds__(256) void mlp1_kernel(const float* __restrict__ xin,
                                                   const float* __restrict__ W1,
                                                   const float* __restrict__ b1,
                                                   float* __restrict__ h) {
    __shared__ float As[32][68];  // [k][m]
    __shared__ float Bs[32][68];  // [k][n]
    const int bm = blockIdx.x;    // 256 row-tiles of 64
    const int bn = blockIdx.y;    // 4 col-tiles of 64
    const int tid = threadIdx.x;
    const int tx = tid & 15, ty = tid >> 4;

    float acc[4][4] = {{0.f}};

    const int arow = tid >> 2;         // 0..63
    const int acol4 = (tid & 3) * 4;   // k offset 0,4,8,12
    const int brow = tid >> 4;         // 0..15 (k)
    const int bcol4 = (tid & 15) * 4;  // 0..60

    const float* xrow = xin + (size_t)(bm * 64 + arow) * DIN;
    const float* wbase = W1 + bn * 64;

    for (int kt = 0; kt < DIN; kt += 32) {
        float4 a0 = *(const float4*)(xrow + kt + acol4);
        float4 a1 = *(const float4*)(xrow + kt + 16 + acol4);
        float4 w0 = *(const float4*)(wbase + (size_t)(kt + brow) * H1 + bcol4);
        float4 w1 = *(const float4*)(wbase + (size_t)(kt + 16 + brow) * H1 + bcol4);
        __syncthreads();
        if (FUSE) {
            As[acol4 + 0][arow] = gelu_exact(a0.x);
            As[acol4 + 1][arow] = gelu_exact(a0.y);
            As[acol4 + 2][arow] = gelu_exact(a0.z);
            As[acol4 + 3][arow] = gelu_exact(a0.w);
            As[16 + acol4 + 0][arow] = gelu_exact(a1.x);
            As[16 + acol4 + 1][arow] = gelu_exact(a1.y);
            As[16 + acol4 + 2][arow] = gelu_exact(a1.z);
            As[16 + acol4 + 3][arow] = gelu_exact(a1.w);
        } else {
            As[acol4 + 0][arow] = a0.x;
            As[acol4 + 1][arow] = a0.y;
            As[acol4 + 2][arow] = a0.z;
            As[acol4 + 3][arow] = a0.w;
            As[16 + acol4 + 0][arow] = a1.x;
            As[16 + acol4 + 1][arow] = a1.y;
            As[16 + acol4 + 2][arow] = a1.z;
            As[16 + acol4 + 3][arow] = a1.w;
        }
        *(float4*)&Bs[brow][bcol4] = w0;
        *(float4*)&Bs[16 + brow][bcol4] = w1;
        __syncthreads();
#pragma unroll
        for (int kk = 0; kk < 32; ++kk) {
            float4 a = *(const float4*)&As[kk][ty * 4];
            float4 b = *(const float4*)&Bs[kk][tx * 4];
            float ar[4] = {a.x, a.y, a.z, a.w};
            float br[4] = {b.x, b.y, b.z, b.w};
#pragma unroll
            for (int i = 0; i < 4; ++i)
#pragma unroll
                for (int j = 0; j < 4; ++j)
                    acc[i][j] = fmaf(ar[i], br[j], acc[i][j]);
        }
    }

    const int row = bm * 64 + ty * 4;
    const int col = bn * 64 + tx * 4;
    float4 bias = *(const float4*)(b1 + col);
#pragma unroll
    for (int i = 0; i < 4; ++i) {
        float4 o;
        o.x = acc[i][0] + bias.x;
        o.y = acc[i][1] + bias.y;
        o.z = acc[i][2] + bias.z;
        o.w = acc[i][3] + bias.w;
        *(float4*)(h + (size_t)(row + i) * H1 + col) = o;
    }
}

// ---------------- Ward clustering with FUSED mlp2 ----------------
// Phase 0 (new, all 4 waves): feats = gelu(h) @ W2 + b2 computed straight into centsT,
// reusing the (not-yet-initialized) cost/G LDS as h-chunk / W2 staging. Per-output FMA
// chain is k=0..255 ascending on gelu_exact'd h, identical to the old mlp2_kernel ->
// centsT bit-identical -> labels bit-identical. Eliminates the mlp2 dispatch + the
// feats global round-trip. Rest of the kernel unchanged from the verified R0 version.
__global__ __launch_bounds__(256) void ward_kernel(const float* __restrict__ h,
                                                   const float* __restrict__ W2,
                                                   const float* __restrict__ b2,
                                                   int* __restrict__ out) {
    __shared__ __align__(16) float cost[NPTS * RSTR];  // 67.6 KB
    __shared__ __align__(16) float G[NPTS * RSTR];     // 67.6 KB Gram matrix
    __shared__ float centsT[32 * CSTR];                // init staging only
    __shared__ unsigned long long rowkey[NPTS];
    __shared__ float sqArr[NPTS];
    __shared__ float szsE[NPTS];
    __shared__ int rnk[NPTS];

    const int b = blockIdx.x;
    const int tid = threadIdx.x;
    const float INF = __builtin_inff();

    // ---- phase 0: fused mlp2 (all 4 waves) ----
    {
        float* w2s = G;      // 256*32 floats = 32 KB  (G not yet live)
        float* hs = cost;    // 32*HSTR floats = 32.9 KB (cost not yet live)
        // stage W2 (row-major [256][32], straight copy)
        for (int i = tid; i < (H1 * DOUT) / 4; i += 256)
            ((float4*)w2s)[i] = ((const float4*)W2)[i];
        const float4 bias = ((const float4*)b2)[tid & 7];
        const float* hb = h + (size_t)b * NPTS * H1;

        const int sr = tid & 31;          // staging row 0..31
        const int sk = (tid >> 5) * 32;   // staging k-base (8 groups of 32)
        const int row = tid >> 3;         // compute row 0..31
        const int col4 = (tid & 7) * 4;   // compute col 0,4,..28

        for (int c = 0; c < 4; ++c) {
            __syncthreads();  // protect hs from previous chunk's readers (and w2s staging on c==0)
            const float* hrow = hb + (size_t)(c * 32 + sr) * H1 + sk;
#pragma unroll
            for (int j = 0; j < 8; ++j) {
                float4 v = ((const float4*)hrow)[j];
                hs[sr * HSTR + sk + 4 * j + 0] = gelu_exact(v.x);
                hs[sr * HSTR + sk + 4 * j + 1] = gelu_exact(v.y);
                hs[sr * HSTR + sk + 4 * j + 2] = gelu_exact(v.z);
                hs[sr * HSTR + sk + 4 * j + 3] = gelu_exact(v.w);
            }
            __syncthreads();
            float a0 = 0.f, a1 = 0.f, a2 = 0.f, a3 = 0.f;
            const float* hr = &hs[row * HSTR];
            for (int k = 0; k < H1; ++k) {
                float a = hr[k];
                float4 w = *(const float4*)&w2s[k * DOUT + col4];
                a0 = fmaf(a, w.x, a0);
                a1 = fmaf(a, w.y, a1);
                a2 = fmaf(a, w.z, a2);
                a3 = fmaf(a, w.w, a3);
            }
            const int gr = c * 32 + row;
            centsT[(col4 + 0) * CSTR + gr] = a0 + bias.x;
            centsT[(col4 + 1) * CSTR + gr] = a1 + bias.y;
            centsT[(col4 + 2) * CSTR + gr] = a2 + bias.z;
            centsT[(col4 + 3) * CSTR + gr] = a3 + bias.w;
        }
    }
    __syncthreads();

    // ---- init (all 4 waves) — unchanged ----
    if (tid < NPTS) {
        float s = 0.f;
#pragma unroll
        for (int d = 0; d < 32; ++d) {
            float v = centsT[d * CSTR + tid];
            s = fmaf(v, v, s);
        }
        sqArr[tid] = s;
    }
    __syncthreads();
    {
        int ti = tid >> 4, tj = tid & 15;
        int I0 = ti * 8, J0 = tj * 8;
        float acc[8][8];
#pragma unroll
        for (int u = 0; u < 8; ++u)
#pragma unroll
            for (int v = 0; v < 8; ++v) acc[u][v] = 0.f;
        for (int d = 0; d < 32; ++d) {
            float a[8], bb[8];
#pragma unroll
            for (int u = 0; u < 8; ++u) a[u] = centsT[d * CSTR + I0 + u];
#pragma unroll
            for (int v = 0; v < 8; ++v) bb[v] = centsT[d * CSTR + J0 + v];
#pragma unroll
            for (int u = 0; u < 8; ++u)
#pragma unroll
                for (int v = 0; v < 8; ++v)
                    acc[u][v] = fmaf(a[u], bb[v], acc[u][v]);
        }
#pragma unroll
        for (int u = 0; u < 8; ++u) {
#pragma unroll
            for (int v = 0; v < 8; ++v) {
                int i = I0 + u, j = J0 + v;
                G[i * RSTR + j] = acc[u][v];
                float d2 = sqArr[i] + sqArr[j] - 2.0f * acc[u][v];
                if (d2 < 0.f) d2 = 0.f;
                float w = (1.0f * 1.0f) / (1.0f + 1.0f + 1e-30f);
                cost[i * RSTR + j] = (i == j) ? INF : w * d2;
            }
        }
    }
    __syncthreads();
    if (tid < NPTS) {
        unsigned long long best = DEADKEY;
        for (int j = 0; j < NPTS; ++j) {
            float v = cost[tid * RSTR + j];
            unsigned long long k = mkkey(v, tid, j);
            if (k < best) best = k;
        }
        rowkey[tid] = best;
    }
    __syncthreads();

    if (tid >= 64) return;  // wave 0 only
    const int lane = tid;
    const int hh = lane & 31;
    const int r0 = lane * 2, r1 = lane * 2 + 1;

    unsigned long long k0 = rowkey[r0], k1 = rowkey[r1];
    float q0 = sqArr[r0], q1 = sqArr[r1];
    float s0 = 1.0f, s1 = 1.0f;
    int lab0 = r0, lab1 = r1;
    unsigned long long alive0 = ~0ull, alive1 = ~0ull;

    for (int it = 0; it < NPTS - KCL; ++it) {
        // P1: global argmin via u32-bits DPP min + ballot (exact flat-index tie-break)
        unsigned bv0 = (unsigned)(k0 >> 32), bv1 = (unsigned)(k1 >> 32);
        unsigned lmin = bv0 < bv1 ? bv0 : bv1;
        unsigned lflat = (bv0 <= bv1) ? (unsigned)(k0 & 0x3FFFu) : (unsigned)(k1 & 0x3FFFu);
        unsigned gmin = wave_umin_bcast(lmin);
        unsigned long long bmask = __ballot(lmin == gmin);
        int lsel = __ffsll(bmask) - 1;
        unsigned flat = (unsigned)__builtin_amdgcn_readlane((int)lflat, lsel);
        int ra = (int)(flat >> 7), ca = (int)(flat & 127u);
        const int i2 = ra < ca ? ra : ca;
        const int j2 = ra < ca ? ca : ra;

        // Gram rows i2, j2 (issued early; only depend on i2/j2)
        float2 gi = *(const float2*)&G[i2 * RSTR + r0];
        float2 gj = *(const float2*)&G[j2 * RSTR + r0];

        float si = readlanef((i2 & 1) ? s1 : s0, i2 >> 1);
        float sj = readlanef((j2 & 1) ? s1 : s0, j2 >> 1);
        const float snew = si + sj;
        const float invs = 1.0f / snew;
        const float wa = si * invs, wb = sj * invs;

        int arg0 = (int)(k0 & 127u), arg1 = (int)(k1 & 127u);
        bool d0 = (s0 > 0.f) && r0 != i2 && r0 != j2 && (arg0 == i2 || arg0 == j2);
        bool d1 = (s1 > 0.f) && r1 != i2 && r1 != j2 && (arg1 == i2 || arg1 == j2);
        unsigned long long m0 = __ballot(d0), m1 = __ballot(d1);

        // scalar Gram entries for qn
        float Gii = readlanef((i2 & 1) ? gi.y : gi.x, i2 >> 1);
        float Gij = readlanef((i2 & 1) ? gj.y : gj.x, i2 >> 1);
        float Gjj = readlanef((j2 & 1) ? gj.y : gj.x, j2 >> 1);
        float dotA = wa * Gii + wb * Gij;
        float dotB = wa * Gij + wb * Gjj;
        float qn = wa * dotA + wb * dotB;

        // per-lane dots with merged cluster (linear Gram update)
        float dot0 = wa * gi.x + wb * gj.x;
        float dot1 = wa * gi.y + wb * gj.y;

        // state updates
        if (lab0 == j2) lab0 = i2;
        if (lab1 == j2) lab1 = i2;
        if (r0 == i2) s0 = snew; else if (r0 == j2) { s0 = 0.f; k0 = DEADKEY; }
        if (r1 == i2) s1 = snew; else if (r1 == j2) { s1 = 0.f; k1 = DEADKEY; }
        if (j2 < 64) alive0 &= ~(1ull << j2); else alive1 &= ~(1ull << (j2 - 64));
        if (r0 == i2) { dot0 = qn; q0 = qn; }
        if (r1 == i2) { dot1 = qn; q1 = qn; }

        // G updates: row i2 (contiguous b64), column i2
        *(float2*)&G[i2 * RSTR + r0] = make_float2(dot0, dot1);
        G[r0 * RSTR + i2] = dot0;
        G[r1 * RSTR + i2] = dot1;

        // cost values for row/col i2
        bool w0 = (s0 > 0.f) && r0 != i2 && r0 != j2;
        bool w1 = (s1 > 0.f) && r1 != i2 && r1 != j2;
        if (w0) {
            float d2 = q0 + qn - 2.0f * dot0;
            if (d2 < 0.f) d2 = 0.f;
            float w = (s0 * snew) / (s0 + snew + 1e-30f);
            float v0 = w * d2;
            cost[r0 * RSTR + i2] = v0;
            cost[i2 * RSTR + r0] = v0;
            if (!d0) {
                unsigned long long nk = mkkey(v0, r0, i2);
                if (nk < k0) k0 = nk;
            }
        }
        if (w1) {
            float d2 = q1 + qn - 2.0f * dot1;
            if (d2 < 0.f) d2 = 0.f;
            float w = (s1 * snew) / (s1 + snew + 1e-30f);
            float v1 = w * d2;
            cost[r1 * RSTR + i2] = v1;
            cost[i2 * RSTR + r1] = v1;
            if (!d1) {
                unsigned long long nk = mkkey(v1, r1, i2);
                if (nk < k1) k1 = nk;
            }
        }

        // rescans: row i2 (always) + dirty rows; 2 rows/round, b128 + alive-mask + u32 half-min
        bool pi = true;
        unsigned long long mm0 = m0, mm1 = m1;
        while (pi | (mm0 != 0ull) | (mm1 != 0ull)) {
            int rA, rB;
            bool hasB = false;
            if (pi) { rA = i2; pi = false; }
            else if (mm0) { int t = __ffsll(mm0) - 1; rA = 2 * t; mm0 &= mm0 - 1; }
            else { int t = __ffsll(mm1) - 1; rA = 2 * t + 1; mm1 &= mm1 - 1; }
            if (mm0) { int t = __ffsll(mm0) - 1; rB = 2 * t; mm0 &= mm0 - 1; hasB = true; }
            else if (mm1) { int t = __ffsll(mm1) - 1; rB = 2 * t + 1; mm1 &= mm1 - 1; hasB = true; }
            else rB = rA;

            int r = (lane < 32) ? rA : rB;
            float4 cv = *(const float4*)&cost[r * RSTR + 4 * hh];
            unsigned long long word = (hh < 16) ? alive0 : alive1;
            unsigned nib = (unsigned)(word >> ((4 * hh) & 63)) & 0xFu;
            unsigned e0 = (nib & 1u) ? __float_as_uint(cv.x) : 0xFFFFFFFFu;
            unsigned e1 = (nib & 2u) ? __float_as_uint(cv.y) : 0xFFFFFFFFu;
            unsigned e2 = (nib & 4u) ? __float_as_uint(cv.z) : 0xFFFFFFFFu;
            unsigned e3 = (nib & 8u) ? __float_as_uint(cv.w) : 0xFFFFFFFFu;
            unsigned m = e0; int c = 0;
            if (e1 < m) { m = e1; c = 1; }
            if (e2 < m) { m = e2; c = 2; }
            if (e3 < m) { m = e3; c = 3; }
            int lcol = 4 * hh + c;
            unsigned hm = half_umin(m);
            unsigned vA = (unsigned)__builtin_amdgcn_readlane((int)hm, 31);
            unsigned vB = (unsigned)__builtin_amdgcn_readlane((int)hm, 63);
            unsigned vref = (lane < 32) ? vA : vB;
            unsigned long long msk = __ballot(m == vref);
            int laneA = __ffsll(msk & 0xFFFFFFFFull) - 1;
            int laneB = 32 + __ffsll(msk >> 32) - 1;
            int colA = __builtin_amdgcn_readlane(lcol, laneA);
            int colB = __builtin_amdgcn_readlane(lcol, laneB);
            unsigned long long keyA = ((unsigned long long)vA << 32) | (unsigned)((rA << 7) | colA);
            unsigned long long keyB = ((unsigned long long)vB << 32) | (unsigned)((rB << 7) | colB);
            if (lane == (rA >> 1)) { if (rA & 1) k1 = keyA; else k0 = keyA; }
            if (hasB && lane == (rB >> 1)) { if (rB & 1) k1 = keyB; else k0 = keyB; }
        }
    }

    // final relabel
    szsE[r0] = s0;
    szsE[r1] = s1;
    __asm__ volatile("s_waitcnt lgkmcnt(0)" ::: "memory");
    if (lane == 0) {
        int c = 0;
        for (int i = 0; i < NPTS; ++i) rnk[i] = (szsE[i] > 0.f) ? c++ : -1;
    }
    __asm__ volatile("s_waitcnt lgkmcnt(0)" ::: "memory");
    out[b * NPTS + r0] = rnk[lab0];
    out[b * NPTS + r1] = rnk[lab1];
}

extern "C" void kernel_launch(void* const* d_in, const int* in_sizes, int n_in,
                              void* d_out, int out_size, void* d_ws, size_t ws_size,
                              hipStream_t stream) {
    const float* x  = (const float*)d_in[0];
    const float* W1 = (const float*)d_in[1];
    const float* b1 = (const float*)d_in[2];
    const float* W2 = (const float*)d_in[3];
    const float* b2 = (const float*)d_in[4];

    float* h = (float*)d_ws;                          // 16 MB
    float* gx = h + (size_t)MROWS * H1;               // 64 MB (if it fits)
    int* out = (int*)d_out;

    const size_t need = ((size_t)MROWS * H1 + (size_t)MROWS * DIN) * 4;
    const bool use_gx = ws_size >= need;

    if (use_gx) {
        gelu_kernel<<<2048, 256, 0, stream>>>(x, gx, MROWS * DIN / 4);
        mlp1_kernel<false><<<dim3(MROWS / 64, H1 / 64), 256, 0, stream>>>(gx, W1, b1, h);
    } else {
        mlp1_kernel<true><<<dim3(MROWS / 64, H1 / 64), 256, 0, stream>>>(x, W1, b1, h);
    }
    ward_kernel<<<BB, 256, 0, stream>>>(h, W2, b2, out);
}

// Round 7
// 432.080 us; speedup vs baseline: 1.0224x; 1.0224x over previous
//
#include <hip/hip_runtime.h>
#include <math.h>

#define BB 128
#define NN 128
#define DIN 1024
#define H1 256
#define DOUT 32
#define KCL 8
#define NPTS 128
#define MROWS (BB*NN)   // 16384
#define CSTR 130        // centsT row stride (words, init staging only)
#define RSTR 132        // cost/G row stride (words, 16B aligned)
#define HSTR 257        // mlp2 h-chunk row stride (odd -> conflict-free reads)
#define DEADKEY 0xFFFFFFFF00000000ull

__device__ __forceinline__ float gelu_exact(float v) {
    return 0.5f * v * (1.0f + erff(v * 0.70710678118654752f));
}

__device__ __forceinline__ unsigned long long mkkey(float v, int r, int j) {
    return ((unsigned long long)__float_as_uint(v) << 32) | (unsigned)((r << 7) | j);
}

__device__ __forceinline__ float readlanef(float v, int lane) {
    return __int_as_float(__builtin_amdgcn_readlane(__float_as_int(v), lane));
}

// u32 min via DPP (costs are >=0 floats: IEEE order == unsigned bit order)
template<int CTRL, int RMASK>
__device__ __forceinline__ unsigned dpp_umin_step(unsigned v) {
    unsigned t = (unsigned)__builtin_amdgcn_update_dpp((int)v, (int)v, CTRL, RMASK, 0xf, false);
    return t < v ? t : v;
}
__device__ __forceinline__ unsigned wave_umin_bcast(unsigned v) {
    v = dpp_umin_step<0x111, 0xf>(v);
    v = dpp_umin_step<0x112, 0xf>(v);
    v = dpp_umin_step<0x114, 0xf>(v);
    v = dpp_umin_step<0x118, 0xf>(v);
    v = dpp_umin_step<0x142, 0xa>(v);
    v = dpp_umin_step<0x143, 0xc>(v);
    return (unsigned)__builtin_amdgcn_readlane((int)v, 63);
}
// lane31 = min(lanes0..31), lane63 = min(lanes32..63)
__device__ __forceinline__ unsigned half_umin(unsigned v) {
    v = dpp_umin_step<0x111, 0xf>(v);
    v = dpp_umin_step<0x112, 0xf>(v);
    v = dpp_umin_step<0x114, 0xf>(v);
    v = dpp_umin_step<0x118, 0xf>(v);
    v = dpp_umin_step<0x142, 0xa>(v);
    return v;
}

// ---------------- gelu precompute: gx = gelu(x), memory-bound ----------------
__global__ __launch_bounds__(256) void gelu_kernel(const float* __restrict__ x,
                                                   float* __restrict__ gx, int n4) {
    int i = blockIdx.x * 256 + threadIdx.x;
    const int stride = gridDim.x * 256;
    for (; i < n4; i += stride) {
        float4 v = ((const float4*)x)[i];
        v.x = gelu_exact(v.x);
        v.y = gelu_exact(v.y);
        v.z = gelu_exact(v.z);
        v.w = gelu_exact(v.w);
        ((float4*)gx)[i] = v;
    }
}

// ---------------- GEMM1: h = A @ W1 + b1 ; R0 structure (64x64, BK=32, grid 1024) ----------------
// FUSE=true: A = gelu(x) applied at staging (fallback). FUSE=false: A = gx (pre-gelu'd).
// NOTE: 3 geometry variants (R2/R3/R5) failed to beat this; 4-blocks/CU overlap is what
// covers the 2-barrier staging drain. Keep frozen.
template<bool FUSE>
__global__ __launch_bounds__(256) void mlp1_kernel(const float* __restrict__ xin,
                                                   const float* __restrict__ W1,
                                                   const float* __restrict__ b1,
                                                   float* __restrict__ h) {
    __shared__ float As[32][68];  // [k][m]
    __shared__ float Bs[32][68];  // [k][n]
    const int bm = blockIdx.x;    // 256 row-tiles of 64
    const int bn = blockIdx.y;    // 4 col-tiles of 64
    const int tid = threadIdx.x;
    const int tx = tid & 15, ty = tid >> 4;

    float acc[4][4] = {{0.f}};

    const int arow = tid >> 2;         // 0..63
    const int acol4 = (tid & 3) * 4;   // k offset 0,4,8,12
    const int brow = tid >> 4;         // 0..15 (k)
    const int bcol4 = (tid & 15) * 4;  // 0..60

    const float* xrow = xin + (size_t)(bm * 64 + arow) * DIN;
    const float* wbase = W1 + bn * 64;

    for (int kt = 0; kt < DIN; kt += 32) {
        float4 a0 = *(const float4*)(xrow + kt + acol4);
        float4 a1 = *(const float4*)(xrow + kt + 16 + acol4);
        float4 w0 = *(const float4*)(wbase + (size_t)(kt + brow) * H1 + bcol4);
        float4 w1 = *(const float4*)(wbase + (size_t)(kt + 16 + brow) * H1 + bcol4);
        __syncthreads();
        if (FUSE) {
            As[acol4 + 0][arow] = gelu_exact(a0.x);
            As[acol4 + 1][arow] = gelu_exact(a0.y);
            As[acol4 + 2][arow] = gelu_exact(a0.z);
            As[acol4 + 3][arow] = gelu_exact(a0.w);
            As[16 + acol4 + 0][arow] = gelu_exact(a1.x);
            As[16 + acol4 + 1][arow] = gelu_exact(a1.y);
            As[16 + acol4 + 2][arow] = gelu_exact(a1.z);
            As[16 + acol4 + 3][arow] = gelu_exact(a1.w);
        } else {
            As[acol4 + 0][arow] = a0.x;
            As[acol4 + 1][arow] = a0.y;
            As[acol4 + 2][arow] = a0.z;
            As[acol4 + 3][arow] = a0.w;
            As[16 + acol4 + 0][arow] = a1.x;
            As[16 + acol4 + 1][arow] = a1.y;
            As[16 + acol4 + 2][arow] = a1.z;
            As[16 + acol4 + 3][arow] = a1.w;
        }
        *(float4*)&Bs[brow][bcol4] = w0;
        *(float4*)&Bs[16 + brow][bcol4] = w1;
        __syncthreads();
#pragma unroll
        for (int kk = 0; kk < 32; ++kk) {
            float4 a = *(const float4*)&As[kk][ty * 4];
            float4 b = *(const float4*)&Bs[kk][tx * 4];
            float ar[4] = {a.x, a.y, a.z, a.w};
            float br[4] = {b.x, b.y, b.z, b.w};
#pragma unroll
            for (int i = 0; i < 4; ++i)
#pragma unroll
                for (int j = 0; j < 4; ++j)
                    acc[i][j] = fmaf(ar[i], br[j], acc[i][j]);
        }
    }

    const int row = bm * 64 + ty * 4;
    const int col = bn * 64 + tx * 4;
    float4 bias = *(const float4*)(b1 + col);
#pragma unroll
    for (int i = 0; i < 4; ++i) {
        float4 o;
        o.x = acc[i][0] + bias.x;
        o.y = acc[i][1] + bias.y;
        o.z = acc[i][2] + bias.z;
        o.w = acc[i][3] + bias.w;
        *(float4*)(h + (size_t)(row + i) * H1 + col) = o;
    }
}

// ---------------- GEMM2: feats = gelu(h) @ W2 + b2 ----------------
// 512 blocks x 32 rows (2 blocks/CU), 1 row x 4 cols per thread.
// k-loop: 1 scalar hs read (broadcast across the 8 col-threads of a row) + 1 w2s float4
// = 2 LDS insts per 4 FMA (old version: 3 insts per 2 FMA). Per-output FMA chain is
// k=0..255 ascending with gelu per element + bias at end -> bit-identical to reference.
// (This mapping was harness-verified bit-exact as R6's ward phase-0.)
__global__ __launch_bounds__(256) void mlp2_kernel(const float* __restrict__ h,
                                                   const float* __restrict__ W2,
                                                   const float* __restrict__ b2,
                                                   float* __restrict__ feats) {
    __shared__ float hs[32 * HSTR];    // 32.9 KB
    __shared__ float w2s[H1 * DOUT];   // 32 KB
    const int blk = blockIdx.x;
    const int tid = threadIdx.x;

    for (int i = tid; i < (H1 * DOUT) / 4; i += 256)
        ((float4*)w2s)[i] = ((const float4*)W2)[i];

    const float* hb = h + (size_t)blk * 32 * H1;
    const int sr = tid & 31;          // staging row 0..31
    const int sk = (tid >> 5) * 32;   // staging k-base (8 groups of 32)
    const float* hrow = hb + (size_t)sr * H1 + sk;
#pragma unroll
    for (int j = 0; j < 8; ++j) {
        float4 v = ((const float4*)hrow)[j];
        hs[sr * HSTR + sk + 4 * j + 0] = gelu_exact(v.x);
        hs[sr * HSTR + sk + 4 * j + 1] = gelu_exact(v.y);
        hs[sr * HSTR + sk + 4 * j + 2] = gelu_exact(v.z);
        hs[sr * HSTR + sk + 4 * j + 3] = gelu_exact(v.w);
    }
    __syncthreads();

    const int row = tid >> 3;         // 0..31
    const int col4 = (tid & 7) * 4;   // 0,4,..,28
    const float4 bias = ((const float4*)b2)[tid & 7];
    float a0 = 0.f, a1 = 0.f, a2 = 0.f, a3 = 0.f;
    const float* hr = &hs[row * HSTR];
    for (int k = 0; k < H1; ++k) {
        float a = hr[k];
        float4 w = *(const float4*)&w2s[k * DOUT + col4];
        a0 = fmaf(a, w.x, a0);
        a1 = fmaf(a, w.y, a1);
        a2 = fmaf(a, w.z, a2);
        a3 = fmaf(a, w.w, a3);
    }
    float4 o;
    o.x = a0 + bias.x;
    o.y = a1 + bias.y;
    o.z = a2 + bias.z;
    o.w = a3 + bias.w;
    *(float4*)(feats + (size_t)(blk * 32 + row) * DOUT + col4) = o;
}

// ---------------- Ward clustering: incremental Gram, i2 folded into rescan loop ----------------
__global__ __launch_bounds__(256) void ward_kernel(const float* __restrict__ feats,
                                                   int* __restrict__ out) {
    __shared__ __align__(16) float cost[NPTS * RSTR];  // 67.6 KB
    __shared__ __align__(16) float G[NPTS * RSTR];     // 67.6 KB Gram matrix
    __shared__ float centsT[32 * CSTR];                // init staging only
    __shared__ unsigned long long rowkey[NPTS];
    __shared__ float sqArr[NPTS];
    __shared__ float szsE[NPTS];
    __shared__ int rnk[NPTS];

    const int b = blockIdx.x;
    const int tid = threadIdx.x;
    const float* f = feats + (size_t)b * NPTS * DOUT;
    const float INF = __builtin_inff();

    // ---- init (all 4 waves) ----
    for (int i = tid; i < NPTS * DOUT; i += 256) {
        int r = i >> 5, d = i & 31;
        centsT[d * CSTR + r] = f[i];
    }
    __syncthreads();
    if (tid < NPTS) {
        float s = 0.f;
#pragma unroll
        for (int d = 0; d < 32; ++d) {
            float v = centsT[d * CSTR + tid];
            s = fmaf(v, v, s);
        }
        sqArr[tid] = s;
    }
    __syncthreads();
    {
        int ti = tid >> 4, tj = tid & 15;
        int I0 = ti * 8, J0 = tj * 8;
        float acc[8][8];
#pragma unroll
        for (int u = 0; u < 8; ++u)
#pragma unroll
            for (int v = 0; v < 8; ++v) acc[u][v] = 0.f;
        for (int d = 0; d < 32; ++d) {
            float a[8], bb[8];
#pragma unroll
            for (int u = 0; u < 8; ++u) a[u] = centsT[d * CSTR + I0 + u];
#pragma unroll
            for (int v = 0; v < 8; ++v) bb[v] = centsT[d * CSTR + J0 + v];
#pragma unroll
            for (int u = 0; u < 8; ++u)
#pragma unroll
                for (int v = 0; v < 8; ++v)
                    acc[u][v] = fmaf(a[u], bb[v], acc[u][v]);
        }
#pragma unroll
        for (int u = 0; u < 8; ++u) {
#pragma unroll
            for (int v = 0; v < 8; ++v) {
                int i = I0 + u, j = J0 + v;
                G[i * RSTR + j] = acc[u][v];
                float d2 = sqArr[i] + sqArr[j] - 2.0f * acc[u][v];
                if (d2 < 0.f) d2 = 0.f;
                float w = (1.0f * 1.0f) / (1.0f + 1.0f + 1e-30f);
                cost[i * RSTR + j] = (i == j) ? INF : w * d2;
            }
        }
    }
    __syncthreads();
    if (tid < NPTS) {
        unsigned long long best = DEADKEY;
        for (int j = 0; j < NPTS; ++j) {
            float v = cost[tid * RSTR + j];
            unsigned long long k = mkkey(v, tid, j);
            if (k < best) best = k;
        }
        rowkey[tid] = best;
    }
    __syncthreads();

    if (tid >= 64) return;  // wave 0 only
    const int lane = tid;
    const int hh = lane & 31;
    const int r0 = lane * 2, r1 = lane * 2 + 1;

    unsigned long long k0 = rowkey[r0], k1 = rowkey[r1];
    float q0 = sqArr[r0], q1 = sqArr[r1];
    float s0 = 1.0f, s1 = 1.0f;
    int lab0 = r0, lab1 = r1;
    unsigned long long alive0 = ~0ull, alive1 = ~0ull;

    for (int it = 0; it < NPTS - KCL; ++it) {
        // P1: global argmin via u32-bits DPP min + ballot (exact flat-index tie-break)
        unsigned bv0 = (unsigned)(k0 >> 32), bv1 = (unsigned)(k1 >> 32);
        unsigned lmin = bv0 < bv1 ? bv0 : bv1;
        unsigned lflat = (bv0 <= bv1) ? (unsigned)(k0 & 0x3FFFu) : (unsigned)(k1 & 0x3FFFu);
        unsigned gmin = wave_umin_bcast(lmin);
        unsigned long long bmask = __ballot(lmin == gmin);
        int lsel = __ffsll(bmask) - 1;
        unsigned flat = (unsigned)__builtin_amdgcn_readlane((int)lflat, lsel);
        int ra = (int)(flat >> 7), ca = (int)(flat & 127u);
        const int i2 = ra < ca ? ra : ca;
        const int j2 = ra < ca ? ca : ra;

        // Gram rows i2, j2 (issued early; only depend on i2/j2)
        float2 gi = *(const float2*)&G[i2 * RSTR + r0];
        float2 gj = *(const float2*)&G[j2 * RSTR + r0];

        float si = readlanef((i2 & 1) ? s1 : s0, i2 >> 1);
        float sj = readlanef((j2 & 1) ? s1 : s0, j2 >> 1);
        const float snew = si + sj;
        const float invs = 1.0f / snew;
        const float wa = si * invs, wb = sj * invs;

        int arg0 = (int)(k0 & 127u), arg1 = (int)(k1 & 127u);
        bool d0 = (s0 > 0.f) && r0 != i2 && r0 != j2 && (arg0 == i2 || arg0 == j2);
        bool d1 = (s1 > 0.f) && r1 != i2 && r1 != j2 && (arg1 == i2 || arg1 == j2);
        unsigned long long m0 = __ballot(d0), m1 = __ballot(d1);

        // scalar Gram entries for qn
        float Gii = readlanef((i2 & 1) ? gi.y : gi.x, i2 >> 1);
        float Gij = readlanef((i2 & 1) ? gj.y : gj.x, i2 >> 1);
        float Gjj = readlanef((j2 & 1) ? gj.y : gj.x, j2 >> 1);
        float dotA = wa * Gii + wb * Gij;
        float dotB = wa * Gij + wb * Gjj;
        float qn = wa * dotA + wb * dotB;

        // per-lane dots with merged cluster (linear Gram update)
        float dot0 = wa * gi.x + wb * gj.x;
        float dot1 = wa * gi.y + wb * gj.y;

        // state updates
        if (lab0 == j2) lab0 = i2;
        if (lab1 == j2) lab1 = i2;
        if (r0 == i2) s0 = snew; else if (r0 == j2) { s0 = 0.f; k0 = DEADKEY; }
        if (r1 == i2) s1 = snew; else if (r1 == j2) { s1 = 0.f; k1 = DEADKEY; }
        if (j2 < 64) alive0 &= ~(1ull << j2); else alive1 &= ~(1ull << (j2 - 64));
        if (r0 == i2) { dot0 = qn; q0 = qn; }
        if (r1 == i2) { dot1 = qn; q1 = qn; }

        // G updates: row i2 (contiguous b64), column i2
        *(float2*)&G[i2 * RSTR + r0] = make_float2(dot0, dot1);
        G[r0 * RSTR + i2] = dot0;
        G[r1 * RSTR + i2] = dot1;

        // cost values for row/col i2
        bool w0 = (s0 > 0.f) && r0 != i2 && r0 != j2;
        bool w1 = (s1 > 0.f) && r1 != i2 && r1 != j2;
        if (w0) {
            float d2 = q0 + qn - 2.0f * dot0;
            if (d2 < 0.f) d2 = 0.f;
            float w = (s0 * snew) / (s0 + snew + 1e-30f);
            float v0 = w * d2;
            cost[r0 * RSTR + i2] = v0;
            cost[i2 * RSTR + r0] = v0;
            if (!d0) {
                unsigned long long nk = mkkey(v0, r0, i2);
                if (nk < k0) k0 = nk;
            }
        }
        if (w1) {
            float d2 = q1 + qn - 2.0f * dot1;
            if (d2 < 0.f) d2 = 0.f;
            float w = (s1 * snew) / (s1 + snew + 1e-30f);
            float v1 = w * d2;
            cost[r1 * RSTR + i2] = v1;
            cost[i2 * RSTR + r1] = v1;
            if (!d1) {
                unsigned long long nk = mkkey(v1, r1, i2);
                if (nk < k1) k1 = nk;
            }
        }

        // rescans: row i2 (always) + dirty rows; 2 rows/round, b128 + alive-mask + u32 half-min
        bool pi = true;
        unsigned long long mm0 = m0, mm1 = m1;
        while (pi | (mm0 != 0ull) | (mm1 != 0ull)) {
            int rA, rB;
            bool hasB = false;
            if (pi) { rA = i2; pi = false; }
            else if (mm0) { int t = __ffsll(mm0) - 1; rA = 2 * t; mm0 &= mm0 - 1; }
            else { int t = __ffsll(mm1) - 1; rA = 2 * t + 1; mm1 &= mm1 - 1; }
            if (mm0) { int t = __ffsll(mm0) - 1; rB = 2 * t; mm0 &= mm0 - 1; hasB = true; }
            else if (mm1) { int t = __ffsll(mm1) - 1; rB = 2 * t + 1; mm1 &= mm1 - 1; hasB = true; }
            else rB = rA;

            int r = (lane < 32) ? rA : rB;
            float4 cv = *(const float4*)&cost[r * RSTR + 4 * hh];
            unsigned long long word = (hh < 16) ? alive0 : alive1;
            unsigned nib = (unsigned)(word >> ((4 * hh) & 63)) & 0xFu;
            unsigned e0 = (nib & 1u) ? __float_as_uint(cv.x) : 0xFFFFFFFFu;
            unsigned e1 = (nib & 2u) ? __float_as_uint(cv.y) : 0xFFFFFFFFu;
            unsigned e2 = (nib & 4u) ? __float_as_uint(cv.z) : 0xFFFFFFFFu;
            unsigned e3 = (nib & 8u) ? __float_as_uint(cv.w) : 0xFFFFFFFFu;
            unsigned m = e0; int c = 0;
            if (e1 < m) { m = e1; c = 1; }
            if (e2 < m) { m = e2; c = 2; }
            if (e3 < m) { m = e3; c = 3; }
            int lcol = 4 * hh + c;
            unsigned hm = half_umin(m);
            unsigned vA = (unsigned)__builtin_amdgcn_readlane((int)hm, 31);
            unsigned vB = (unsigned)__builtin_amdgcn_readlane((int)hm, 63);
            unsigned vref = (lane < 32) ? vA : vB;
            unsigned long long msk = __ballot(m == vref);
            int laneA = __ffsll(msk & 0xFFFFFFFFull) - 1;
            int laneB = 32 + __ffsll(msk >> 32) - 1;
            int colA = __builtin_amdgcn_readlane(lcol, laneA);
            int colB = __builtin_amdgcn_readlane(lcol, laneB);
            unsigned long long keyA = ((unsigned long long)vA << 32) | (unsigned)((rA << 7) | colA);
            unsigned long long keyB = ((unsigned long long)vB << 32) | (unsigned)((rB << 7) | colB);
            if (lane == (rA >> 1)) { if (rA & 1) k1 = keyA; else k0 = keyA; }
            if (hasB && lane == (rB >> 1)) { if (rB & 1) k1 = keyB; else k0 = keyB; }
        }
    }

    // final relabel
    szsE[r0] = s0;
    szsE[r1] = s1;
    __asm__ volatile("s_waitcnt lgkmcnt(0)" ::: "memory");
    if (lane == 0) {
        int c = 0;
        for (int i = 0; i < NPTS; ++i) rnk[i] = (szsE[i] > 0.f) ? c++ : -1;
    }
    __asm__ volatile("s_waitcnt lgkmcnt(0)" ::: "memory");
    out[b * NPTS + r0] = rnk[lab0];
    out[b * NPTS + r1] = rnk[lab1];
}

extern "C" void kernel_launch(void* const* d_in, const int* in_sizes, int n_in,
                              void* d_out, int out_size, void* d_ws, size_t ws_size,
                              hipStream_t stream) {
    const float* x  = (const float*)d_in[0];
    const float* W1 = (const float*)d_in[1];
    const float* b1 = (const float*)d_in[2];
    const float* W2 = (const float*)d_in[3];
    const float* b2 = (const float*)d_in[4];

    float* h = (float*)d_ws;                          // 16 MB
    float* feats = h + (size_t)MROWS * H1;            // 2 MB
    float* gx = feats + (size_t)MROWS * DOUT;         // 64 MB (if it fits)
    int* out = (int*)d_out;

    const size_t need = ((size_t)MROWS * H1 + (size_t)MROWS * DOUT + (size_t)MROWS * DIN) * 4;
    const bool use_gx = ws_size >= need;

    if (use_gx) {
        gelu_kernel<<<2048, 256, 0, stream>>>(x, gx, MROWS * DIN / 4);
        mlp1_kernel<false><<<dim3(MROWS / 64, H1 / 64), 256, 0, stream>>>(gx, W1, b1, h);
    } else {
        mlp1_kernel<true><<<dim3(MROWS / 64, H1 / 64), 256, 0, stream>>>(x, W1, b1, h);
    }
    mlp2_kernel<<<MROWS / 32, 256, 0, stream>>>(h, W2, b2, feats);
    ward_kernel<<<BB, 256, 0, stream>>>(feats, out);
}

// Round 8
// 427.350 us; speedup vs baseline: 1.0337x; 1.0111x over previous
//
#include <hip/hip_runtime.h>
#include <math.h>

#define BB 128
#define NN 128
#define DIN 1024
#define H1 256
#define DOUT 32
#define KCL 8
#define NPTS 128
#define MROWS (BB*NN)   // 16384
#define CSTR 130        // centsT row stride (words, init staging only)
#define RSTR 132        // cost/G row stride (words, 16B aligned)
#define HSTR 257        // mlp2 h-chunk row stride (odd -> conflict-free reads)
#define DEADKEY 0xFFFFFFFF00000000ull

__device__ __forceinline__ float gelu_exact(float v) {
    return 0.5f * v * (1.0f + erff(v * 0.70710678118654752f));
}

__device__ __forceinline__ unsigned long long mkkey(float v, int r, int j) {
    return ((unsigned long long)__float_as_uint(v) << 32) | (unsigned)((r << 7) | j);
}

__device__ __forceinline__ float readlanef(float v, int lane) {
    return __int_as_float(__builtin_amdgcn_readlane(__float_as_int(v), lane));
}

// u32 min via DPP (costs are >=0 floats: IEEE order == unsigned bit order)
template<int CTRL, int RMASK>
__device__ __forceinline__ unsigned dpp_umin_step(unsigned v) {
    unsigned t = (unsigned)__builtin_amdgcn_update_dpp((int)v, (int)v, CTRL, RMASK, 0xf, false);
    return t < v ? t : v;
}
__device__ __forceinline__ unsigned wave_umin_bcast(unsigned v) {
    v = dpp_umin_step<0x111, 0xf>(v);
    v = dpp_umin_step<0x112, 0xf>(v);
    v = dpp_umin_step<0x114, 0xf>(v);
    v = dpp_umin_step<0x118, 0xf>(v);
    v = dpp_umin_step<0x142, 0xa>(v);
    v = dpp_umin_step<0x143, 0xc>(v);
    return (unsigned)__builtin_amdgcn_readlane((int)v, 63);
}
// lane31 = min(lanes0..31), lane63 = min(lanes32..63)
__device__ __forceinline__ unsigned half_umin(unsigned v) {
    v = dpp_umin_step<0x111, 0xf>(v);
    v = dpp_umin_step<0x112, 0xf>(v);
    v = dpp_umin_step<0x114, 0xf>(v);
    v = dpp_umin_step<0x118, 0xf>(v);
    v = dpp_umin_step<0x142, 0xa>(v);
    return v;
}

// ---------------- gelu precompute: gx = gelu(x), memory-bound ----------------
__global__ __launch_bounds__(256) void gelu_kernel(const float* __restrict__ x,
                                                   float* __restrict__ gx, int n4) {
    int i = blockIdx.x * 256 + threadIdx.x;
    const int stride = gridDim.x * 256;
    for (; i < n4; i += stride) {
        float4 v = ((const float4*)x)[i];
        v.x = gelu_exact(v.x);
        v.y = gelu_exact(v.y);
        v.z = gelu_exact(v.z);
        v.w = gelu_exact(v.w);
        ((float4*)gx)[i] = v;
    }
}

// ---------------- GEMM1: h = A @ W1 + b1 ----------------
// 64x64 tile, 4x4 microtile (frozen geometry), BK=64: 16 kt-iterations -> HALF the
// barrier+vmcnt drains of the BK=32 version (R5 showed the kernel is neither VALU- nor
// LDS-BW-saturated; the drain count is the remaining lever). Grid (bn=4, bm=256) with
// x fastest so the 4 blocks sharing A-rows are dispatch-adjacent (gx L2 reuse).
// k-ascending FMA order preserved -> h bit-identical.
// FUSE=true: A = gelu(x) at staging (fallback). FUSE=false: A = gx (pre-gelu'd).
template<bool FUSE>
__global__ __launch_bounds__(256) void mlp1_kernel(const float* __restrict__ xin,
                                                   const float* __restrict__ W1,
                                                   const float* __restrict__ b1,
                                                   float* __restrict__ h) {
    __shared__ float As[64][68];  // [k][m] 17.4 KB
    __shared__ float Bs[64][68];  // [k][n] 17.4 KB
    const int bn = blockIdx.x;    // 4 col-tiles of 64
    const int bm = blockIdx.y;    // 256 row-tiles of 64
    const int tid = threadIdx.x;
    const int tx = tid & 15, ty = tid >> 4;

    float acc[4][4] = {{0.f}};

    const int arow = tid >> 2;         // 0..63
    const int kc   = (tid & 3) * 4;    // k offset 0,4,8,12 (within each 16-group)
    const int brow = tid >> 4;         // 0..15 (k)
    const int bcol4 = (tid & 15) * 4;  // 0..60

    const float* xrow = xin + (size_t)(bm * 64 + arow) * DIN;
    const float* wbase = W1 + bn * 64;

    for (int kt = 0; kt < DIN; kt += 64) {
        float4 a0 = *(const float4*)(xrow + kt + kc);
        float4 a1 = *(const float4*)(xrow + kt + kc + 16);
        float4 a2 = *(const float4*)(xrow + kt + kc + 32);
        float4 a3 = *(const float4*)(xrow + kt + kc + 48);
        float4 w0 = *(const float4*)(wbase + (size_t)(kt + brow) * H1 + bcol4);
        float4 w1 = *(const float4*)(wbase + (size_t)(kt + 16 + brow) * H1 + bcol4);
        float4 w2 = *(const float4*)(wbase + (size_t)(kt + 32 + brow) * H1 + bcol4);
        float4 w3 = *(const float4*)(wbase + (size_t)(kt + 48 + brow) * H1 + bcol4);
        __syncthreads();
        if (FUSE) {
            As[kc + 0][arow] = gelu_exact(a0.x);
            As[kc + 1][arow] = gelu_exact(a0.y);
            As[kc + 2][arow] = gelu_exact(a0.z);
            As[kc + 3][arow] = gelu_exact(a0.w);
            As[16 + kc + 0][arow] = gelu_exact(a1.x);
            As[16 + kc + 1][arow] = gelu_exact(a1.y);
            As[16 + kc + 2][arow] = gelu_exact(a1.z);
            As[16 + kc + 3][arow] = gelu_exact(a1.w);
            As[32 + kc + 0][arow] = gelu_exact(a2.x);
            As[32 + kc + 1][arow] = gelu_exact(a2.y);
            As[32 + kc + 2][arow] = gelu_exact(a2.z);
            As[32 + kc + 3][arow] = gelu_exact(a2.w);
            As[48 + kc + 0][arow] = gelu_exact(a3.x);
            As[48 + kc + 1][arow] = gelu_exact(a3.y);
            As[48 + kc + 2][arow] = gelu_exact(a3.z);
            As[48 + kc + 3][arow] = gelu_exact(a3.w);
        } else {
            As[kc + 0][arow] = a0.x;
            As[kc + 1][arow] = a0.y;
            As[kc + 2][arow] = a0.z;
            As[kc + 3][arow] = a0.w;
            As[16 + kc + 0][arow] = a1.x;
            As[16 + kc + 1][arow] = a1.y;
            As[16 + kc + 2][arow] = a1.z;
            As[16 + kc + 3][arow] = a1.w;
            As[32 + kc + 0][arow] = a2.x;
            As[32 + kc + 1][arow] = a2.y;
            As[32 + kc + 2][arow] = a2.z;
            As[32 + kc + 3][arow] = a2.w;
            As[48 + kc + 0][arow] = a3.x;
            As[48 + kc + 1][arow] = a3.y;
            As[48 + kc + 2][arow] = a3.z;
            As[48 + kc + 3][arow] = a3.w;
        }
        *(float4*)&Bs[brow][bcol4] = w0;
        *(float4*)&Bs[16 + brow][bcol4] = w1;
        *(float4*)&Bs[32 + brow][bcol4] = w2;
        *(float4*)&Bs[48 + brow][bcol4] = w3;
        __syncthreads();
#pragma unroll
        for (int kk = 0; kk < 64; ++kk) {
            float4 a = *(const float4*)&As[kk][ty * 4];
            float4 b = *(const float4*)&Bs[kk][tx * 4];
            float ar[4] = {a.x, a.y, a.z, a.w};
            float br[4] = {b.x, b.y, b.z, b.w};
#pragma unroll
            for (int i = 0; i < 4; ++i)
#pragma unroll
                for (int j = 0; j < 4; ++j)
                    acc[i][j] = fmaf(ar[i], br[j], acc[i][j]);
        }
    }

    const int row = bm * 64 + ty * 4;
    const int col = bn * 64 + tx * 4;
    float4 bias = *(const float4*)(b1 + col);
#pragma unroll
    for (int i = 0; i < 4; ++i) {
        float4 o;
        o.x = acc[i][0] + bias.x;
        o.y = acc[i][1] + bias.y;
        o.z = acc[i][2] + bias.z;
        o.w = acc[i][3] + bias.w;
        *(float4*)(h + (size_t)(row + i) * H1 + col) = o;
    }
}

// ---------------- GEMM2: feats = gelu(h) @ W2 + b2 (R7 version, verified) ----------------
__global__ __launch_bounds__(256) void mlp2_kernel(const float* __restrict__ h,
                                                   const float* __restrict__ W2,
                                                   const float* __restrict__ b2,
                                                   float* __restrict__ feats) {
    __shared__ float hs[32 * HSTR];    // 32.9 KB
    __shared__ float w2s[H1 * DOUT];   // 32 KB
    const int blk = blockIdx.x;
    const int tid = threadIdx.x;

    for (int i = tid; i < (H1 * DOUT) / 4; i += 256)
        ((float4*)w2s)[i] = ((const float4*)W2)[i];

    const float* hb = h + (size_t)blk * 32 * H1;
    const int sr = tid & 31;          // staging row 0..31
    const int sk = (tid >> 5) * 32;   // staging k-base (8 groups of 32)
    const float* hrow = hb + (size_t)sr * H1 + sk;
#pragma unroll
    for (int j = 0; j < 8; ++j) {
        float4 v = ((const float4*)hrow)[j];
        hs[sr * HSTR + sk + 4 * j + 0] = gelu_exact(v.x);
        hs[sr * HSTR + sk + 4 * j + 1] = gelu_exact(v.y);
        hs[sr * HSTR + sk + 4 * j + 2] = gelu_exact(v.z);
        hs[sr * HSTR + sk + 4 * j + 3] = gelu_exact(v.w);
    }
    __syncthreads();

    const int row = tid >> 3;         // 0..31
    const int col4 = (tid & 7) * 4;   // 0,4,..,28
    const float4 bias = ((const float4*)b2)[tid & 7];
    float a0 = 0.f, a1 = 0.f, a2 = 0.f, a3 = 0.f;
    const float* hr = &hs[row * HSTR];
    for (int k = 0; k < H1; ++k) {
        float a = hr[k];
        float4 w = *(const float4*)&w2s[k * DOUT + col4];
        a0 = fmaf(a, w.x, a0);
        a1 = fmaf(a, w.y, a1);
        a2 = fmaf(a, w.z, a2);
        a3 = fmaf(a, w.w, a3);
    }
    float4 o;
    o.x = a0 + bias.x;
    o.y = a1 + bias.y;
    o.z = a2 + bias.z;
    o.w = a3 + bias.w;
    *(float4*)(feats + (size_t)(blk * 32 + row) * DOUT + col4) = o;
}

// ---------------- Ward clustering: incremental Gram, i2 folded into rescan loop ----------------
__global__ __launch_bounds__(256) void ward_kernel(const float* __restrict__ feats,
                                                   int* __restrict__ out) {
    __shared__ __align__(16) float cost[NPTS * RSTR];  // 67.6 KB
    __shared__ __align__(16) float G[NPTS * RSTR];     // 67.6 KB Gram matrix
    __shared__ float centsT[32 * CSTR];                // init staging only
    __shared__ unsigned long long rowkey[NPTS];
    __shared__ float sqArr[NPTS];
    __shared__ float szsE[NPTS];
    __shared__ int rnk[NPTS];

    const int b = blockIdx.x;
    const int tid = threadIdx.x;
    const float* f = feats + (size_t)b * NPTS * DOUT;
    const float INF = __builtin_inff();

    // ---- init (all 4 waves) ----
    for (int i = tid; i < NPTS * DOUT; i += 256) {
        int r = i >> 5, d = i & 31;
        centsT[d * CSTR + r] = f[i];
    }
    __syncthreads();
    if (tid < NPTS) {
        float s = 0.f;
#pragma unroll
        for (int d = 0; d < 32; ++d) {
            float v = centsT[d * CSTR + tid];
            s = fmaf(v, v, s);
        }
        sqArr[tid] = s;
    }
    __syncthreads();
    {
        int ti = tid >> 4, tj = tid & 15;
        int I0 = ti * 8, J0 = tj * 8;
        float acc[8][8];
#pragma unroll
        for (int u = 0; u < 8; ++u)
#pragma unroll
            for (int v = 0; v < 8; ++v) acc[u][v] = 0.f;
        for (int d = 0; d < 32; ++d) {
            float a[8], bb[8];
#pragma unroll
            for (int u = 0; u < 8; ++u) a[u] = centsT[d * CSTR + I0 + u];
#pragma unroll
            for (int v = 0; v < 8; ++v) bb[v] = centsT[d * CSTR + J0 + v];
#pragma unroll
            for (int u = 0; u < 8; ++u)
#pragma unroll
                for (int v = 0; v < 8; ++v)
                    acc[u][v] = fmaf(a[u], bb[v], acc[u][v]);
        }
#pragma unroll
        for (int u = 0; u < 8; ++u) {
#pragma unroll
            for (int v = 0; v < 8; ++v) {
                int i = I0 + u, j = J0 + v;
                G[i * RSTR + j] = acc[u][v];
                float d2 = sqArr[i] + sqArr[j] - 2.0f * acc[u][v];
                if (d2 < 0.f) d2 = 0.f;
                float w = (1.0f * 1.0f) / (1.0f + 1.0f + 1e-30f);
                cost[i * RSTR + j] = (i == j) ? INF : w * d2;
            }
        }
    }
    __syncthreads();
    if (tid < NPTS) {
        unsigned long long best = DEADKEY;
        for (int j = 0; j < NPTS; ++j) {
            float v = cost[tid * RSTR + j];
            unsigned long long k = mkkey(v, tid, j);
            if (k < best) best = k;
        }
        rowkey[tid] = best;
    }
    __syncthreads();

    if (tid >= 64) return;  // wave 0 only
    const int lane = tid;
    const int hh = lane & 31;
    const int r0 = lane * 2, r1 = lane * 2 + 1;

    unsigned long long k0 = rowkey[r0], k1 = rowkey[r1];
    float q0 = sqArr[r0], q1 = sqArr[r1];
    float s0 = 1.0f, s1 = 1.0f;
    int lab0 = r0, lab1 = r1;
    unsigned long long alive0 = ~0ull, alive1 = ~0ull;

    for (int it = 0; it < NPTS - KCL; ++it) {
        // P1: global argmin via u32-bits DPP min + ballot (exact flat-index tie-break)
        unsigned bv0 = (unsigned)(k0 >> 32), bv1 = (unsigned)(k1 >> 32);
        unsigned lmin = bv0 < bv1 ? bv0 : bv1;
        unsigned lflat = (bv0 <= bv1) ? (unsigned)(k0 & 0x3FFFu) : (unsigned)(k1 & 0x3FFFu);
        unsigned gmin = wave_umin_bcast(lmin);
        unsigned long long bmask = __ballot(lmin == gmin);
        int lsel = __ffsll(bmask) - 1;
        unsigned flat = (unsigned)__builtin_amdgcn_readlane((int)lflat, lsel);
        int ra = (int)(flat >> 7), ca = (int)(flat & 127u);
        const int i2 = ra < ca ? ra : ca;
        const int j2 = ra < ca ? ca : ra;

        // Gram rows i2, j2 (issued early; only depend on i2/j2)
        float2 gi = *(const float2*)&G[i2 * RSTR + r0];
        float2 gj = *(const float2*)&G[j2 * RSTR + r0];

        float si = readlanef((i2 & 1) ? s1 : s0, i2 >> 1);
        float sj = readlanef((j2 & 1) ? s1 : s0, j2 >> 1);
        const float snew = si + sj;
        const float invs = 1.0f / snew;
        const float wa = si * invs, wb = sj * invs;

        int arg0 = (int)(k0 & 127u), arg1 = (int)(k1 & 127u);
        bool d0 = (s0 > 0.f) && r0 != i2 && r0 != j2 && (arg0 == i2 || arg0 == j2);
        bool d1 = (s1 > 0.f) && r1 != i2 && r1 != j2 && (arg1 == i2 || arg1 == j2);
        unsigned long long m0 = __ballot(d0), m1 = __ballot(d1);

        // scalar Gram entries for qn
        float Gii = readlanef((i2 & 1) ? gi.y : gi.x, i2 >> 1);
        float Gij = readlanef((i2 & 1) ? gj.y : gj.x, i2 >> 1);
        float Gjj = readlanef((j2 & 1) ? gj.y : gj.x, j2 >> 1);
        float dotA = wa * Gii + wb * Gij;
        float dotB = wa * Gij + wb * Gjj;
        float qn = wa * dotA + wb * dotB;

        // per-lane dots with merged cluster (linear Gram update)
        float dot0 = wa * gi.x + wb * gj.x;
        float dot1 = wa * gi.y + wb * gj.y;

        // state updates
        if (lab0 == j2) lab0 = i2;
        if (lab1 == j2) lab1 = i2;
        if (r0 == i2) s0 = snew; else if (r0 == j2) { s0 = 0.f; k0 = DEADKEY; }
        if (r1 == i2) s1 = snew; else if (r1 == j2) { s1 = 0.f; k1 = DEADKEY; }
        if (j2 < 64) alive0 &= ~(1ull << j2); else alive1 &= ~(1ull << (j2 - 64));
        if (r0 == i2) { dot0 = qn; q0 = qn; }
        if (r1 == i2) { dot1 = qn; q1 = qn; }

        // G updates: row i2 (contiguous b64), column i2
        *(float2*)&G[i2 * RSTR + r0] = make_float2(dot0, dot1);
        G[r0 * RSTR + i2] = dot0;
        G[r1 * RSTR + i2] = dot1;

        // cost values for row/col i2
        bool w0 = (s0 > 0.f) && r0 != i2 && r0 != j2;
        bool w1 = (s1 > 0.f) && r1 != i2 && r1 != j2;
        if (w0) {
            float d2 = q0 + qn - 2.0f * dot0;
            if (d2 < 0.f) d2 = 0.f;
            float w = (s0 * snew) / (s0 + snew + 1e-30f);
            float v0 = w * d2;
            cost[r0 * RSTR + i2] = v0;
            cost[i2 * RSTR + r0] = v0;
            if (!d0) {
                unsigned long long nk = mkkey(v0, r0, i2);
                if (nk < k0) k0 = nk;
            }
        }
        if (w1) {
            float d2 = q1 + qn - 2.0f * dot1;
            if (d2 < 0.f) d2 = 0.f;
            float w = (s1 * snew) / (s1 + snew + 1e-30f);
            float v1 = w * d2;
            cost[r1 * RSTR + i2] = v1;
            cost[i2 * RSTR + r1] = v1;
            if (!d1) {
                unsigned long long nk = mkkey(v1, r1, i2);
                if (nk < k1) k1 = nk;
            }
        }

        // rescans: row i2 (always) + dirty rows; 2 rows/round, b128 + alive-mask + u32 half-min
        bool pi = true;
        unsigned long long mm0 = m0, mm1 = m1;
        while (pi | (mm0 != 0ull) | (mm1 != 0ull)) {
            int rA, rB;
            bool hasB = false;
            if (pi) { rA = i2; pi = false; }
            else if (mm0) { int t = __ffsll(mm0) - 1; rA = 2 * t; mm0 &= mm0 - 1; }
            else { int t = __ffsll(mm1) - 1; rA = 2 * t + 1; mm1 &= mm1 - 1; }
            if (mm0) { int t = __ffsll(mm0) - 1; rB = 2 * t; mm0 &= mm0 - 1; hasB = true; }
            else if (mm1) { int t = __ffsll(mm1) - 1; rB = 2 * t + 1; mm1 &= mm1 - 1; hasB = true; }
            else rB = rA;

            int r = (lane < 32) ? rA : rB;
            float4 cv = *(const float4*)&cost[r * RSTR + 4 * hh];
            unsigned long long word = (hh < 16) ? alive0 : alive1;
            unsigned nib = (unsigned)(word >> ((4 * hh) & 63)) & 0xFu;
            unsigned e0 = (nib & 1u) ? __float_as_uint(cv.x) : 0xFFFFFFFFu;
            unsigned e1 = (nib & 2u) ? __float_as_uint(cv.y) : 0xFFFFFFFFu;
            unsigned e2 = (nib & 4u) ? __float_as_uint(cv.z) : 0xFFFFFFFFu;
            unsigned e3 = (nib & 8u) ? __float_as_uint(cv.w) : 0xFFFFFFFFu;
            unsigned m = e0; int c = 0;
            if (e1 < m) { m = e1; c = 1; }
            if (e2 < m) { m = e2; c = 2; }
            if (e3 < m) { m = e3; c = 3; }
            int lcol = 4 * hh + c;
            unsigned hm = half_umin(m);
            unsigned vA = (unsigned)__builtin_amdgcn_readlane((int)hm, 31);
            unsigned vB = (unsigned)__builtin_amdgcn_readlane((int)hm, 63);
            unsigned vref = (lane < 32) ? vA : vB;
            unsigned long long msk = __ballot(m == vref);
            int laneA = __ffsll(msk & 0xFFFFFFFFull) - 1;
            int laneB = 32 + __ffsll(msk >> 32) - 1;
            int colA = __builtin_amdgcn_readlane(lcol, laneA);
            int colB = __builtin_amdgcn_readlane(lcol, laneB);
            unsigned long long keyA = ((unsigned long long)vA << 32) | (unsigned)((rA << 7) | colA);
            unsigned long long keyB = ((unsigned long long)vB << 32) | (unsigned)((rB << 7) | colB);
            if (lane == (rA >> 1)) { if (rA & 1) k1 = keyA; else k0 = keyA; }
            if (hasB && lane == (rB >> 1)) { if (rB & 1) k1 = keyB; else k0 = keyB; }
        }
    }

    // final relabel
    szsE[r0] = s0;
    szsE[r1] = s1;
    __asm__ volatile("s_waitcnt lgkmcnt(0)" ::: "memory");
    if (lane == 0) {
        int c = 0;
        for (int i = 0; i < NPTS; ++i) rnk[i] = (szsE[i] > 0.f) ? c++ : -1;
    }
    __asm__ volatile("s_waitcnt lgkmcnt(0)" ::: "memory");
    out[b * NPTS + r0] = rnk[lab0];
    out[b * NPTS + r1] = rnk[lab1];
}

extern "C" void kernel_launch(void* const* d_in, const int* in_sizes, int n_in,
                              void* d_out, int out_size, void* d_ws, size_t ws_size,
                              hipStream_t stream) {
    const float* x  = (const float*)d_in[0];
    const float* W1 = (const float*)d_in[1];
    const float* b1 = (const float*)d_in[2];
    const float* W2 = (const float*)d_in[3];
    const float* b2 = (const float*)d_in[4];

    float* h = (float*)d_ws;                          // 16 MB
    float* feats = h + (size_t)MROWS * H1;            // 2 MB
    float* gx = feats + (size_t)MROWS * DOUT;         // 64 MB (if it fits)
    int* out = (int*)d_out;

    const size_t need = ((size_t)MROWS * H1 + (size_t)MROWS * DOUT + (size_t)MROWS * DIN) * 4;
    const bool use_gx = ws_size >= need;

    if (use_gx) {
        gelu_kernel<<<2048, 256, 0, stream>>>(x, gx, MROWS * DIN / 4);
        mlp1_kernel<false><<<dim3(H1 / 64, MROWS / 64), 256, 0, stream>>>(gx, W1, b1, h);
    } else {
        mlp1_kernel<true><<<dim3(H1 / 64, MROWS / 64), 256, 0, stream>>>(x, W1, b1, h);
    }
    mlp2_kernel<<<MROWS / 32, 256, 0, stream>>>(h, W2, b2, feats);
    ward_kernel<<<BB, 256, 0, stream>>>(feats, out);
}